// Round 9
// baseline (405.568 us; speedup 1.0000x reference)
//
#include <hip/hip_runtime.h>

namespace {
constexpr int B = 1024, Q = 128, P = 32, N = 128, D = 64, K = 160;

// ---------------- mean distance over cdist(x, y_pos) ----------------
__global__ __launch_bounds__(256) void k_meandist(
    const float* __restrict__ x, const float* __restrict__ y_pos,
    double* __restrict__ ws) {
  __shared__ float Yp[P][D];
  __shared__ float ysq[P];
  __shared__ float red[4];
  const int b = blockIdx.x, tid = threadIdx.x;
  const float* yb = y_pos + (size_t)b * P * D;
  for (int i = tid; i < P * D / 4; i += 256)
    reinterpret_cast<float4*>(&Yp[0][0])[i] = reinterpret_cast<const float4*>(yb)[i];
  __syncthreads();
  if (tid < P) {
    float s = 0.f;
    for (int d = 0; d < D; ++d) { float v = Yp[tid][d]; s = fmaf(v, v, s); }
    ysq[tid] = s;
  }
  __syncthreads();
  const int q = tid >> 1, ph = tid & 1;
  const float* xq = x + ((size_t)b * Q + q) * D;
  float acc[16];
#pragma unroll
  for (int j = 0; j < 16; ++j) acc[j] = 0.f;
  float xsq = 0.f;
#pragma unroll 1
  for (int d4 = 0; d4 < 16; ++d4) {
    float4 xv = reinterpret_cast<const float4*>(xq)[d4];
    xsq = fmaf(xv.x, xv.x, fmaf(xv.y, xv.y, fmaf(xv.z, xv.z, fmaf(xv.w, xv.w, xsq))));
#pragma unroll
    for (int j = 0; j < 16; ++j) {
      float4 yv = reinterpret_cast<const float4*>(&Yp[ph * 16 + j][0])[d4];
      acc[j] = fmaf(xv.x, yv.x, fmaf(xv.y, yv.y, fmaf(xv.z, yv.z, fmaf(xv.w, yv.w, acc[j]))));
    }
  }
  float dsum = 0.f;
#pragma unroll
  for (int j = 0; j < 16; ++j) {
    float d2 = xsq + ysq[ph * 16 + j] - 2.f * acc[j];
    dsum += sqrtf(fmaxf(d2, 0.f));
  }
#pragma unroll
  for (int m = 1; m < 64; m <<= 1) dsum += __shfl_xor(dsum, m);
  if ((tid & 63) == 0) red[tid >> 6] = dsum;
  __syncthreads();
  if (tid == 0)
    atomicAdd(ws, (double)(red[0] + red[1] + red[2] + red[3]));
}

// ================= K2: coefficient kernel (dist + sums + C -> global) ======
// 512 threads, one block/batch, 64.5 KB LDS -> 2 blocks/CU co-resident.
// waves_per_eu(2,4): min=2 -> 128-VGPR budget (measured rule budget=256/min),
// max=4 -> allows 16 waves/CU residency (R7 lesson: max caps residency).
// Max live ~90 regs (dist phase): no spill (R5-class phases only).
__global__
__attribute__((amdgpu_flat_work_group_size(512, 512)))
__attribute__((amdgpu_waves_per_eu(2, 4)))
void k_coeff(
    const float* __restrict__ x, const float* __restrict__ y_pos,
    const float* __restrict__ y_neg, double* __restrict__ ws,
    float4* __restrict__ C4g) {
  // LDS (floats): Y4 [160][16]f4 rotated | X4c [128][8]f4 | rss/css/uss/vss | ysq
  __shared__ __align__(16) float SM[16128];
  float4* Y4  = (float4*)SM;                 // [0,10240)
  float4* X4c = (float4*)(SM + 10240);       // [10240,14336)
  float* rss = SM + 14336;                   // [3][128]
  float* css = SM + 14720;                   // [3][160]
  float* uss = SM + 15200;                   // [3][128]
  float* vss = SM + 15584;                   // [3][128]
  float* ysq = SM + 15968;                   // [160]

  const int b = blockIdx.x, tid = threadIdx.x;
  const float4* yn4 = (const float4*)(y_neg + (size_t)b * N * D);
  const float4* yp4 = (const float4*)(y_pos + (size_t)b * P * D);
  const float4* xg  = (const float4*)(x + (size_t)b * Q * D);

  for (int idx = tid; idx < K * 16; idx += 512) {
    int k = idx >> 4, d4 = idx & 15;
    float4 v = (k < N) ? yn4[k * 16 + d4] : yp4[(k - N) * 16 + d4];
    Y4[k * 16 + ((d4 + k) & 15)] = v;
  }
  if (tid < 384) { rss[tid] = 0.f; uss[tid] = 0.f; vss[tid] = 0.f; }
  __syncthreads();
  if (tid < K) {
    float s = 0.f;
#pragma unroll
    for (int c = 0; c < 16; ++c) {
      float4 v = Y4[tid * 16 + ((c + tid) & 15)];
      s = fmaf(v.x, v.x, fmaf(v.y, v.y, fmaf(v.z, v.z, fmaf(v.w, v.w, s))));
    }
    ysq[tid] = s;
  }

  const int qg = tid & 15, kt = tid >> 4;   // q in [8qg,8qg+8), k = kt+32j
  const int qb = qg * 8;

  float zz[8][5];
  float xsq8[8];
#pragma unroll
  for (int i = 0; i < 8; ++i) {
    xsq8[i] = 0.f;
#pragma unroll
    for (int j = 0; j < 5; ++j) zz[i][j] = 0.f;
  }

#pragma unroll 1
  for (int ch = 0; ch < 2; ++ch) {
    __syncthreads();
#pragma unroll
    for (int r = 0; r < 2; ++r) {
      int idx = tid + 512 * r;
      int q = idx >> 3, c = idx & 7;
      X4c[q * 8 + ((c + (q >> 3)) & 7)] = xg[q * 16 + ch * 8 + c];
    }
    __syncthreads();
#pragma unroll
    for (int d4 = 0; d4 < 8; ++d4) {
      const int rx = (d4 + qg) & 7;
      float4 xv[8];
#pragma unroll
      for (int i = 0; i < 8; ++i) xv[i] = X4c[(qb + i) * 8 + rx];
#pragma unroll
      for (int i = 0; i < 8; ++i)
        xsq8[i] = fmaf(xv[i].x, xv[i].x, fmaf(xv[i].y, xv[i].y,
                  fmaf(xv[i].z, xv[i].z, fmaf(xv[i].w, xv[i].w, xsq8[i]))));
      const int gd4 = ch * 8 + d4;
#pragma unroll
      for (int j = 0; j < 5; ++j) {
        const int k_ = kt + 32 * j;
        float4 yv = Y4[k_ * 16 + ((gd4 + k_) & 15)];
#pragma unroll
        for (int i = 0; i < 8; ++i)
          zz[i][j] = fmaf(xv[i].x, yv.x, fmaf(xv[i].y, yv.y,
                     fmaf(xv[i].z, yv.z, fmaf(xv[i].w, yv.w, zz[i][j]))));
      }
    }
  }
  const float meand = (float)(ws[0] * (1.0 / ((double)B * Q * P)));
  const float invt2 = 1.0f / fmaxf(meand, 1e-6f);
#pragma unroll
  for (int i = 0; i < 8; ++i)
#pragma unroll
    for (int j = 0; j < 5; ++j) {
      const int k_ = kt + 32 * j;
      float d2 = xsq8[i] + ysq[k_] - 2.f * zz[i][j];
      zz[i][j] = __expf(-sqrtf(fmaxf(d2, 0.f)) * invt2);
    }

  // pass 1: row/col sums per temp (z, z^2, z^10)
#pragma unroll
  for (int t = 0; t < 3; ++t) {
    float ers[8] = {0.f,0.f,0.f,0.f,0.f,0.f,0.f,0.f};
    float ecs[5] = {0.f,0.f,0.f,0.f,0.f};
#pragma unroll
    for (int i = 0; i < 8; ++i)
#pragma unroll
      for (int j = 0; j < 5; ++j) {
        float z = zz[i][j], f;
        if (t == 2) f = z;
        else if (t == 1) f = z * z;
        else { float z2 = z * z, z4 = z2 * z2; f = z4 * z4 * z2; }
        ers[i] += f; ecs[j] += f;
      }
#pragma unroll
    for (int j = 0; j < 5; ++j) {
      float v = ecs[j];
      v += __shfl_xor(v, 1); v += __shfl_xor(v, 2);
      v += __shfl_xor(v, 4); v += __shfl_xor(v, 8);
      if (qg == 0) css[t * 160 + kt + 32 * j] = v;
    }
#pragma unroll
    for (int i = 0; i < 8; ++i) {
      float v = ers[i];
      v += __shfl_xor(v, 16); v += __shfl_xor(v, 32);
      if ((kt & 3) == 0) atomicAdd(&rss[t * 128 + qb + i], v);
    }
  }
  __syncthreads();
  if (tid < 480) css[tid] = rsqrtf(css[tid]);
  __syncthreads();

  // pass 2: sum_pos (uss) / sum_neg (vss) of e*ics per (temp, q)
#pragma unroll
  for (int t = 0; t < 3; ++t) {
    float icr[5];
#pragma unroll
    for (int j = 0; j < 5; ++j) icr[j] = css[t * 160 + kt + 32 * j];
    float uu[8] = {0.f,0.f,0.f,0.f,0.f,0.f,0.f,0.f};
    float vv[8] = {0.f,0.f,0.f,0.f,0.f,0.f,0.f,0.f};
#pragma unroll
    for (int i = 0; i < 8; ++i)
#pragma unroll
      for (int j = 0; j < 5; ++j) {
        float z = zz[i][j], f;
        if (t == 2) f = z;
        else if (t == 1) f = z * z;
        else { float z2 = z * z, z4 = z2 * z2; f = z4 * z4 * z2; }
        float a = f * icr[j];
        if (j == 4) uu[i] += a; else vv[i] += a;   // j==4 <=> k>=128 <=> pos
      }
#pragma unroll
    for (int i = 0; i < 8; ++i) {
      float u = uu[i];
      u += __shfl_xor(u, 16); u += __shfl_xor(u, 32);
      float v = vv[i];
      v += __shfl_xor(v, 16); v += __shfl_xor(v, 32);
      if ((kt & 3) == 0) {
        atomicAdd(&uss[t * 128 + qb + i], u);
        atomicAdd(&vss[t * 128 + qb + i], v);
      }
    }
  }
  __syncthreads();
  if (tid < 384) {
    float inv = 1.0f / rss[tid];
    uss[tid] *= inv;
    vss[tid] *= inv;
  }
  __syncthreads();

  // coefficient production -> GLOBAL C[b][k][q] (coalesced f4 stores)
#pragma unroll
  for (int j = 0; j < 5; ++j) {
    const int k_ = kt + 32 * j;
    const bool pos = (j == 4);
    const float ic0 = css[k_], ic1 = css[160 + k_], ic2 = css[320 + k_];
    float c0a[8];
#pragma unroll
    for (int i = 0; i < 8; ++i) {
      const int q2 = qb + i;
      float a0 = pos ? vss[q2]       : uss[q2];
      float a1 = pos ? vss[128 + q2] : uss[128 + q2];
      float a2 = pos ? vss[256 + q2] : uss[256 + q2];
      float z = zz[i][j], z2 = z * z, z4 = z2 * z2, z10 = z4 * z4 * z2;
      float c = fmaf(z, ic2 * a2, fmaf(z2, ic1 * a1, z10 * (ic0 * a0)));
      c0a[i] = pos ? c : -c;
    }
    const size_t base = ((size_t)b * K + k_) * 32;
    C4g[base + 2 * qg]     = make_float4(c0a[0], c0a[1], c0a[2], c0a[3]);
    C4g[base + 2 * qg + 1] = make_float4(c0a[4], c0a[5], c0a[6], c0a[7]);
  }
}

// ================= K3: drift GEMM (C from global, Y from LDS) + loss =======
// 512 threads, one block/batch, ~41 KB LDS. dr[4][8]=32 acc regs, live ~70.
__global__
__attribute__((amdgpu_flat_work_group_size(512, 512)))
__attribute__((amdgpu_waves_per_eu(2, 4)))
void k_gemm(
    const float* __restrict__ y_pos, const float* __restrict__ y_neg,
    const float4* __restrict__ C4g, double* __restrict__ ws) {
  __shared__ __align__(16) float SM[10240];
  __shared__ double redd[4];
  float4* Y4 = (float4*)SM;

  const int b = blockIdx.x, tid = threadIdx.x;
  const float4* yn4 = (const float4*)(y_neg + (size_t)b * N * D);
  const float4* yp4 = (const float4*)(y_pos + (size_t)b * P * D);
  for (int idx = tid; idx < K * 16; idx += 512) {
    int k = idx >> 4, d4 = idx & 15;
    float4 v = (k < N) ? yn4[k * 16 + d4] : yp4[(k - N) * 16 + d4];
    Y4[k * 16 + ((d4 + k) & 15)] = v;
  }
  __syncthreads();

  const int qc = (tid >> 3) & 31, dc = tid & 7, kc = tid >> 8;
  float dr[4][8];
#pragma unroll
  for (int i = 0; i < 4; ++i)
#pragma unroll
    for (int n = 0; n < 8; ++n) dr[i][n] = 0.f;

  const size_t cbase = (size_t)b * K * 32 + qc;
#pragma unroll 4
  for (int kk = 0; kk < 80; ++kk) {
    const int k_ = kc * 80 + kk;
    float4 cg = C4g[cbase + (size_t)k_ * 32];
    float4 y0 = Y4[k_ * 16 + ((2 * dc + k_) & 15)];
    float4 y1 = Y4[k_ * 16 + ((2 * dc + 1 + k_) & 15)];
#define GACC(ii, cv)                               \
    dr[ii][0] = fmaf(cv, y0.x, dr[ii][0]);         \
    dr[ii][1] = fmaf(cv, y0.y, dr[ii][1]);         \
    dr[ii][2] = fmaf(cv, y0.z, dr[ii][2]);         \
    dr[ii][3] = fmaf(cv, y0.w, dr[ii][3]);         \
    dr[ii][4] = fmaf(cv, y1.x, dr[ii][4]);         \
    dr[ii][5] = fmaf(cv, y1.y, dr[ii][5]);         \
    dr[ii][6] = fmaf(cv, y1.z, dr[ii][6]);         \
    dr[ii][7] = fmaf(cv, y1.w, dr[ii][7]);
    GACC(0, cg.x) GACC(1, cg.y) GACC(2, cg.z) GACC(3, cg.w)
#undef GACC
  }
  __syncthreads();

  // merge kc halves (reuse Y region) + loss
  float4* FB = Y4;
  if (kc == 1) {
#pragma unroll
    for (int i = 0; i < 4; ++i) {
      const int q = qc * 4 + i;
#pragma unroll
      for (int w = 0; w < 2; ++w)
        FB[q * 16 + ((2 * dc + w + q) & 15)] =
            make_float4(dr[i][w*4], dr[i][w*4+1], dr[i][w*4+2], dr[i][w*4+3]);
    }
  }
  __syncthreads();
  if (kc == 0) {
    float tot = 0.f;
#pragma unroll
    for (int i = 0; i < 4; ++i) {
      const int q = qc * 4 + i;
#pragma unroll
      for (int w = 0; w < 2; ++w) {
        float4 v = FB[q * 16 + ((2 * dc + w + q) & 15)];
        float a0 = dr[i][w*4]   + v.x;
        float a1 = dr[i][w*4+1] + v.y;
        float a2 = dr[i][w*4+2] + v.z;
        float a3 = dr[i][w*4+3] + v.w;
        tot = fmaf(a0, a0, tot); tot = fmaf(a1, a1, tot);
        tot = fmaf(a2, a2, tot); tot = fmaf(a3, a3, tot);
      }
    }
#pragma unroll
    for (int m = 1; m < 64; m <<= 1) tot += __shfl_xor(tot, m);
    if ((tid & 63) == 0) redd[tid >> 6] = (double)tot;
  }
  __syncthreads();
  if (tid == 0)
    atomicAdd(ws + 1, redd[0] + redd[1] + redd[2] + redd[3]);
}

// ================= fallback: R5 fused kernel (verified, 208 us) ============
__global__
__attribute__((amdgpu_flat_work_group_size(512, 512)))
__attribute__((amdgpu_waves_per_eu(2, 2)))
void k_drift_fused(
    const float* __restrict__ x, const float* __restrict__ y_pos,
    const float* __restrict__ y_neg, double* __restrict__ ws) {
  __shared__ __align__(16) float SM[33296];
  float4* Y4 = (float4*)SM;
  float4* X4 = (float4*)(SM + 10240);
  float*  Cs = SM + 10240;
  float4* C4 = (float4*)(SM + 10240);
  float* rss = SM + 31360;
  float* css = SM + 31744;
  float* uss = SM + 32224;
  float* vss = SM + 32608;
  float* ysq = SM + 32992;
  float* xsq = SM + 33152;
  double* redd = (double*)(SM + 33280);

  const int b = blockIdx.x, tid = threadIdx.x;
  const float4* yn4 = (const float4*)(y_neg + (size_t)b * N * D);
  const float4* yp4 = (const float4*)(y_pos + (size_t)b * P * D);
  const float4* xg  = (const float4*)(x + (size_t)b * Q * D);

  for (int idx = tid; idx < K * 16; idx += 512) {
    int k = idx >> 4, d4 = idx & 15;
    float4 v = (k < N) ? yn4[k * 16 + d4] : yp4[(k - N) * 16 + d4];
    Y4[k * 16 + ((d4 + k) & 15)] = v;
  }
  for (int idx = tid; idx < Q * 16; idx += 512) {
    int q = idx >> 4, d4 = idx & 15;
    X4[q * 16 + ((d4 + (q >> 3)) & 15)] = xg[q * 16 + d4];
  }
  if (tid < 384) { rss[tid] = 0.f; uss[tid] = 0.f; vss[tid] = 0.f; }
  __syncthreads();
  if (tid < K) {
    float s = 0.f;
#pragma unroll
    for (int c = 0; c < 16; ++c) {
      float4 v = Y4[tid * 16 + ((c + tid) & 15)];
      s = fmaf(v.x, v.x, fmaf(v.y, v.y, fmaf(v.z, v.z, fmaf(v.w, v.w, s))));
    }
    ysq[tid] = s;
  }
  if (tid < Q) {
    float s = 0.f;
#pragma unroll
    for (int c = 0; c < 16; ++c) {
      float4 v = X4[tid * 16 + ((c + tid) & 15)];
      s = fmaf(v.x, v.x, fmaf(v.y, v.y, fmaf(v.z, v.z, fmaf(v.w, v.w, s))));
    }
    xsq[tid] = s;
  }
  __syncthreads();

  const int qg = tid & 15, kt = tid >> 4;
  const int qb = qg * 8, kb0 = kt * 5;

  float zz[8][5];
#pragma unroll
  for (int i = 0; i < 8; ++i)
#pragma unroll
    for (int j = 0; j < 5; ++j) zz[i][j] = 0.f;

#pragma unroll 2
  for (int d4 = 0; d4 < 16; ++d4) {
    float4 yv[5];
#pragma unroll
    for (int j = 0; j < 5; ++j) {
      int k = kb0 + j;
      yv[j] = Y4[k * 16 + ((d4 + k) & 15)];
    }
    const int rx = (d4 + qg) & 15;
#pragma unroll
    for (int i = 0; i < 8; ++i) {
      float4 xv = X4[(qb + i) * 16 + rx];
#pragma unroll
      for (int j = 0; j < 5; ++j)
        zz[i][j] = fmaf(xv.x, yv[j].x, fmaf(xv.y, yv[j].y,
                   fmaf(xv.z, yv[j].z, fmaf(xv.w, yv[j].w, zz[i][j]))));
    }
  }

  const float meand = (float)(ws[0] * (1.0 / ((double)B * Q * P)));
  const float invt2 = 1.0f / fmaxf(meand, 1e-6f);
#pragma unroll
  for (int i = 0; i < 8; ++i)
#pragma unroll
    for (int j = 0; j < 5; ++j) {
      float d2 = xsq[qb + i] + ysq[kb0 + j] - 2.f * zz[i][j];
      zz[i][j] = __expf(-sqrtf(fmaxf(d2, 0.f)) * invt2);
    }

#pragma unroll
  for (int t = 0; t < 3; ++t) {
    float ers[8] = {0.f,0.f,0.f,0.f,0.f,0.f,0.f,0.f};
    float ecs[5] = {0.f,0.f,0.f,0.f,0.f};
#pragma unroll
    for (int i = 0; i < 8; ++i)
#pragma unroll
      for (int j = 0; j < 5; ++j) {
        float z = zz[i][j], f;
        if (t == 2) f = z;
        else if (t == 1) f = z * z;
        else { float z2 = z * z, z4 = z2 * z2; f = z4 * z4 * z2; }
        ers[i] += f; ecs[j] += f;
      }
#pragma unroll
    for (int j = 0; j < 5; ++j) {
      float v = ecs[j];
      v += __shfl_xor(v, 1); v += __shfl_xor(v, 2);
      v += __shfl_xor(v, 4); v += __shfl_xor(v, 8);
      if (qg == 0) css[t * 160 + kb0 + j] = v;
    }
#pragma unroll
    for (int i = 0; i < 8; ++i) {
      float v = ers[i];
      v += __shfl_xor(v, 16); v += __shfl_xor(v, 32);
      if ((kt & 3) == 0) atomicAdd(&rss[t * 128 + qb + i], v);
    }
  }
  __syncthreads();
  if (tid < 480) css[tid] = rsqrtf(css[tid]);
  __syncthreads();

#pragma unroll
  for (int t = 0; t < 3; ++t) {
    float icr[5];
#pragma unroll
    for (int j = 0; j < 5; ++j) icr[j] = css[t * 160 + kb0 + j];
    float uu[8] = {0.f,0.f,0.f,0.f,0.f,0.f,0.f,0.f};
    float vv[8] = {0.f,0.f,0.f,0.f,0.f,0.f,0.f,0.f};
#pragma unroll
    for (int i = 0; i < 8; ++i)
#pragma unroll
      for (int j = 0; j < 5; ++j) {
        float z = zz[i][j], f;
        if (t == 2) f = z;
        else if (t == 1) f = z * z;
        else { float z2 = z * z, z4 = z2 * z2; f = z4 * z4 * z2; }
        float a = f * icr[j];
        bool pos = (kb0 + j >= N);
        uu[i] += pos ? a : 0.f;
        vv[i] += pos ? 0.f : a;
      }
#pragma unroll
    for (int i = 0; i < 8; ++i) {
      float u = uu[i];
      u += __shfl_xor(u, 16); u += __shfl_xor(u, 32);
      float v = vv[i];
      v += __shfl_xor(v, 16); v += __shfl_xor(v, 32);
      if ((kt & 3) == 0) {
        atomicAdd(&uss[t * 128 + qb + i], u);
        atomicAdd(&vss[t * 128 + qb + i], v);
      }
    }
  }
  __syncthreads();
  if (tid < 384) {
    float inv = 1.0f / rss[tid];
    uss[tid] *= inv;
    vss[tid] *= inv;
  }
  __syncthreads();

  {
    float ic0[5], ic1[5], ic2[5];
#pragma unroll
    for (int j = 0; j < 5; ++j) {
      ic0[j] = css[0 * 160 + kb0 + j];
      ic1[j] = css[1 * 160 + kb0 + j];
      ic2[j] = css[2 * 160 + kb0 + j];
    }
#pragma unroll
    for (int i = 0; i < 8; ++i) {
      const int q2 = qb + i;
      float u0 = uss[q2], u1 = uss[128 + q2], u2 = uss[256 + q2];
      float v0 = vss[q2], v1 = vss[128 + q2], v2 = vss[256 + q2];
#pragma unroll
      for (int j = 0; j < 5; ++j) {
        const int k = kb0 + j;
        float z = zz[i][j], z2 = z * z, z4 = z2 * z2, z10 = z4 * z4 * z2;
        bool pos = (k >= N);
        float a0 = pos ? v0 : u0, a1 = pos ? v1 : u1, a2 = pos ? v2 : u2;
        float c = fmaf(z, ic2[j] * a2, fmaf(z2, ic1[j] * a1, z10 * (ic0[j] * a0)));
        Cs[k * 132 + q2] = pos ? c : -c;
      }
    }
  }
  __syncthreads();

  const int kc = tid >> 8, qc = (tid >> 3) & 31, dc = tid & 7;
  float dr[4][8];
#pragma unroll
  for (int i = 0; i < 4; ++i)
#pragma unroll
    for (int n = 0; n < 8; ++n) dr[i][n] = 0.f;

#pragma unroll 4
  for (int kk = 0; kk < 80; ++kk) {
    const int k = kc * 80 + kk;
    float4 ca = C4[k * 33 + qc];
    float4 y0 = Y4[k * 16 + ((dc * 2 + k) & 15)];
    float4 y1 = Y4[k * 16 + ((dc * 2 + 1 + k) & 15)];
#define GACC(ii, cv)                               \
    dr[ii][0] = fmaf(cv, y0.x, dr[ii][0]);         \
    dr[ii][1] = fmaf(cv, y0.y, dr[ii][1]);         \
    dr[ii][2] = fmaf(cv, y0.z, dr[ii][2]);         \
    dr[ii][3] = fmaf(cv, y0.w, dr[ii][3]);         \
    dr[ii][4] = fmaf(cv, y1.x, dr[ii][4]);         \
    dr[ii][5] = fmaf(cv, y1.y, dr[ii][5]);         \
    dr[ii][6] = fmaf(cv, y1.z, dr[ii][6]);         \
    dr[ii][7] = fmaf(cv, y1.w, dr[ii][7]);
    GACC(0, ca.x) GACC(1, ca.y) GACC(2, ca.z) GACC(3, ca.w)
#undef GACC
  }
  __syncthreads();

  float4* FB = Y4;
  if (kc == 1) {
#pragma unroll
    for (int i = 0; i < 4; ++i) {
      const int q = qc * 4 + i;
#pragma unroll
      for (int w = 0; w < 2; ++w)
        FB[q * 16 + ((dc * 2 + w + qc) & 15)] =
            make_float4(dr[i][w*4], dr[i][w*4+1], dr[i][w*4+2], dr[i][w*4+3]);
    }
  }
  __syncthreads();
  if (kc == 0) {
    float tot = 0.f;
#pragma unroll
    for (int i = 0; i < 4; ++i) {
      const int q = qc * 4 + i;
#pragma unroll
      for (int w = 0; w < 2; ++w) {
        float4 v = FB[q * 16 + ((dc * 2 + w + qc) & 15)];
        float a0 = dr[i][w*4]   + v.x;
        float a1 = dr[i][w*4+1] + v.y;
        float a2 = dr[i][w*4+2] + v.z;
        float a3 = dr[i][w*4+3] + v.w;
        tot = fmaf(a0, a0, tot); tot = fmaf(a1, a1, tot);
        tot = fmaf(a2, a2, tot); tot = fmaf(a3, a3, tot);
      }
    }
#pragma unroll
    for (int m = 1; m < 64; m <<= 1) tot += __shfl_xor(tot, m);
    if ((tid & 63) == 0) redd[tid >> 6] = (double)tot;
  }
  __syncthreads();
  if (tid == 0)
    atomicAdd(ws + 1, redd[0] + redd[1] + redd[2] + redd[3]);
}

__global__ void k_final(const double* __restrict__ ws, float* __restrict__ out) {
  out[0] = (float)(ws[1] / ((double)B * Q * D));
}

}  // namespace

extern "C" void kernel_launch(void* const* d_in, const int* in_sizes, int n_in,
                              void* d_out, int out_size, void* d_ws, size_t ws_size,
                              hipStream_t stream) {
  const float* x = (const float*)d_in[0];
  const float* y_pos = (const float*)d_in[1];
  const float* y_neg = (const float*)d_in[2];
  float* out = (float*)d_out;
  double* ws = (double*)d_ws;

  const size_t c_bytes = (size_t)B * K * Q * sizeof(float);   // 80 MB
  hipMemsetAsync(d_ws, 0, 2 * sizeof(double), stream);
  k_meandist<<<B, 256, 0, stream>>>(x, y_pos, ws);
  if (ws_size >= 64 + c_bytes) {
    float4* C4g = (float4*)((char*)d_ws + 64);
    k_coeff<<<B, 512, 0, stream>>>(x, y_pos, y_neg, ws, C4g);
    k_gemm<<<B, 512, 0, stream>>>(y_pos, y_neg, C4g, ws);
  } else {
    k_drift_fused<<<B, 512, 0, stream>>>(x, y_pos, y_neg, ws);
  }
  k_final<<<1, 1, 0, stream>>>(ws, out);
}

// Round 10
// 261.341 us; speedup vs baseline: 1.5519x; 1.5519x over previous
//
#include <hip/hip_runtime.h>

namespace {
constexpr int B = 1024, Q = 128, P = 32, N = 128, D = 64, K = 160;

// ---------------- mean distance over cdist(x, y_pos) ----------------
__global__ __launch_bounds__(256) void k_meandist(
    const float* __restrict__ x, const float* __restrict__ y_pos,
    double* __restrict__ ws) {
  __shared__ float Yp[P][D];
  __shared__ float ysq[P];
  __shared__ float red[4];
  const int b = blockIdx.x, tid = threadIdx.x;
  const float* yb = y_pos + (size_t)b * P * D;
  for (int i = tid; i < P * D / 4; i += 256)
    reinterpret_cast<float4*>(&Yp[0][0])[i] = reinterpret_cast<const float4*>(yb)[i];
  __syncthreads();
  if (tid < P) {
    float s = 0.f;
    for (int d = 0; d < D; ++d) { float v = Yp[tid][d]; s = fmaf(v, v, s); }
    ysq[tid] = s;
  }
  __syncthreads();
  const int q = tid >> 1, ph = tid & 1;
  const float* xq = x + ((size_t)b * Q + q) * D;
  float acc[16];
#pragma unroll
  for (int j = 0; j < 16; ++j) acc[j] = 0.f;
  float xsq = 0.f;
#pragma unroll 1
  for (int d4 = 0; d4 < 16; ++d4) {
    float4 xv = reinterpret_cast<const float4*>(xq)[d4];
    xsq = fmaf(xv.x, xv.x, fmaf(xv.y, xv.y, fmaf(xv.z, xv.z, fmaf(xv.w, xv.w, xsq))));
#pragma unroll
    for (int j = 0; j < 16; ++j) {
      float4 yv = reinterpret_cast<const float4*>(&Yp[ph * 16 + j][0])[d4];
      acc[j] = fmaf(xv.x, yv.x, fmaf(xv.y, yv.y, fmaf(xv.z, yv.z, fmaf(xv.w, yv.w, acc[j]))));
    }
  }
  float dsum = 0.f;
#pragma unroll
  for (int j = 0; j < 16; ++j) {
    float d2 = xsq + ysq[ph * 16 + j] - 2.f * acc[j];
    dsum += sqrtf(fmaxf(d2, 0.f));
  }
#pragma unroll
  for (int m = 1; m < 64; m <<= 1) dsum += __shfl_xor(dsum, m);
  if ((tid & 63) == 0) red[tid >> 6] = dsum;
  __syncthreads();
  if (tid == 0)
    atomicAdd(ws, (double)(red[0] + red[1] + red[2] + red[3]));
}

// ================= K2: coefficient kernel (dist + sums + C -> global) ======
// 512 threads, one block/batch, 64.5 KB LDS -> 2 blocks/CU co-resident.
// waves_per_eu(2,4): min=2 -> 128-VGPR budget; max=4 -> 16-wave residency.
// R9 lesson: the dist loop's xv[8] batch (32 regs live under a fully
// unrolled d4 loop) was the spiller (374 MB scratch). R5-proven shape
// instead: yv[5] per d4, ONE xv at a time in the i-loop -> live ~75.
__global__
__attribute__((amdgpu_flat_work_group_size(512, 512)))
__attribute__((amdgpu_waves_per_eu(2, 4)))
void k_coeff(
    const float* __restrict__ x, const float* __restrict__ y_pos,
    const float* __restrict__ y_neg, double* __restrict__ ws,
    float4* __restrict__ C4g) {
  // LDS (floats): Y4 [160][16]f4 rotated | X4c [128][8]f4 | rss/css/uss/vss | ysq
  __shared__ __align__(16) float SM[16128];
  float4* Y4  = (float4*)SM;                 // [0,10240)
  float4* X4c = (float4*)(SM + 10240);       // [10240,14336)
  float* rss = SM + 14336;                   // [3][128]
  float* css = SM + 14720;                   // [3][160]
  float* uss = SM + 15200;                   // [3][128]
  float* vss = SM + 15584;                   // [3][128]
  float* ysq = SM + 15968;                   // [160]

  const int b = blockIdx.x, tid = threadIdx.x;
  const float4* yn4 = (const float4*)(y_neg + (size_t)b * N * D);
  const float4* yp4 = (const float4*)(y_pos + (size_t)b * P * D);
  const float4* xg  = (const float4*)(x + (size_t)b * Q * D);

  for (int idx = tid; idx < K * 16; idx += 512) {
    int k = idx >> 4, d4 = idx & 15;
    float4 v = (k < N) ? yn4[k * 16 + d4] : yp4[(k - N) * 16 + d4];
    Y4[k * 16 + ((d4 + k) & 15)] = v;
  }
  if (tid < 384) { rss[tid] = 0.f; uss[tid] = 0.f; vss[tid] = 0.f; }
  __syncthreads();
  if (tid < K) {
    float s = 0.f;
#pragma unroll
    for (int c = 0; c < 16; ++c) {
      float4 v = Y4[tid * 16 + ((c + tid) & 15)];
      s = fmaf(v.x, v.x, fmaf(v.y, v.y, fmaf(v.z, v.z, fmaf(v.w, v.w, s))));
    }
    ysq[tid] = s;
  }

  const int qg = tid & 15, kt = tid >> 4;   // q in [8qg,8qg+8), k = kt+32j
  const int qb = qg * 8;

  float zz[8][5];
  float xsq8[8];
#pragma unroll
  for (int i = 0; i < 8; ++i) {
    xsq8[i] = 0.f;
#pragma unroll
    for (int j = 0; j < 5; ++j) zz[i][j] = 0.f;
  }

  // ---- dist phase, R5-style register discipline ----
#pragma unroll 1
  for (int ch = 0; ch < 2; ++ch) {
    __syncthreads();
#pragma unroll
    for (int r = 0; r < 2; ++r) {
      int idx = tid + 512 * r;
      int q = idx >> 3, c = idx & 7;
      X4c[q * 8 + ((c + (q >> 3)) & 7)] = xg[q * 16 + ch * 8 + c];
    }
    __syncthreads();
#pragma unroll 2
    for (int d4 = 0; d4 < 8; ++d4) {
      const int gd4 = ch * 8 + d4;
      float4 yv[5];
#pragma unroll
      for (int j = 0; j < 5; ++j) {
        const int k_ = kt + 32 * j;
        yv[j] = Y4[k_ * 16 + ((gd4 + k_) & 15)];
      }
      const int rx = (d4 + qg) & 7;
#pragma unroll
      for (int i = 0; i < 8; ++i) {
        float4 xv = X4c[(qb + i) * 8 + rx];
        xsq8[i] = fmaf(xv.x, xv.x, fmaf(xv.y, xv.y,
                  fmaf(xv.z, xv.z, fmaf(xv.w, xv.w, xsq8[i]))));
#pragma unroll
        for (int j = 0; j < 5; ++j)
          zz[i][j] = fmaf(xv.x, yv[j].x, fmaf(xv.y, yv[j].y,
                     fmaf(xv.z, yv[j].z, fmaf(xv.w, yv[j].w, zz[i][j]))));
      }
    }
  }
  const float meand = (float)(ws[0] * (1.0 / ((double)B * Q * P)));
  const float invt2 = 1.0f / fmaxf(meand, 1e-6f);
#pragma unroll
  for (int i = 0; i < 8; ++i)
#pragma unroll
    for (int j = 0; j < 5; ++j) {
      const int k_ = kt + 32 * j;
      float d2 = xsq8[i] + ysq[k_] - 2.f * zz[i][j];
      zz[i][j] = __expf(-sqrtf(fmaxf(d2, 0.f)) * invt2);
    }

  // pass 1: row/col sums per temp (z, z^2, z^10)
#pragma unroll
  for (int t = 0; t < 3; ++t) {
    float ers[8] = {0.f,0.f,0.f,0.f,0.f,0.f,0.f,0.f};
    float ecs[5] = {0.f,0.f,0.f,0.f,0.f};
#pragma unroll
    for (int i = 0; i < 8; ++i)
#pragma unroll
      for (int j = 0; j < 5; ++j) {
        float z = zz[i][j], f;
        if (t == 2) f = z;
        else if (t == 1) f = z * z;
        else { float z2 = z * z, z4 = z2 * z2; f = z4 * z4 * z2; }
        ers[i] += f; ecs[j] += f;
      }
#pragma unroll
    for (int j = 0; j < 5; ++j) {
      float v = ecs[j];
      v += __shfl_xor(v, 1); v += __shfl_xor(v, 2);
      v += __shfl_xor(v, 4); v += __shfl_xor(v, 8);
      if (qg == 0) css[t * 160 + kt + 32 * j] = v;
    }
#pragma unroll
    for (int i = 0; i < 8; ++i) {
      float v = ers[i];
      v += __shfl_xor(v, 16); v += __shfl_xor(v, 32);
      if ((kt & 3) == 0) atomicAdd(&rss[t * 128 + qb + i], v);
    }
  }
  __syncthreads();
  if (tid < 480) css[tid] = rsqrtf(css[tid]);
  __syncthreads();

  // pass 2: sum_pos (uss) / sum_neg (vss) of e*ics per (temp, q)
#pragma unroll
  for (int t = 0; t < 3; ++t) {
    float icr[5];
#pragma unroll
    for (int j = 0; j < 5; ++j) icr[j] = css[t * 160 + kt + 32 * j];
    float uu[8] = {0.f,0.f,0.f,0.f,0.f,0.f,0.f,0.f};
    float vv[8] = {0.f,0.f,0.f,0.f,0.f,0.f,0.f,0.f};
#pragma unroll
    for (int i = 0; i < 8; ++i)
#pragma unroll
      for (int j = 0; j < 5; ++j) {
        float z = zz[i][j], f;
        if (t == 2) f = z;
        else if (t == 1) f = z * z;
        else { float z2 = z * z, z4 = z2 * z2; f = z4 * z4 * z2; }
        float a = f * icr[j];
        if (j == 4) uu[i] += a; else vv[i] += a;   // j==4 <=> k>=128 <=> pos
      }
#pragma unroll
    for (int i = 0; i < 8; ++i) {
      float u = uu[i];
      u += __shfl_xor(u, 16); u += __shfl_xor(u, 32);
      float v = vv[i];
      v += __shfl_xor(v, 16); v += __shfl_xor(v, 32);
      if ((kt & 3) == 0) {
        atomicAdd(&uss[t * 128 + qb + i], u);
        atomicAdd(&vss[t * 128 + qb + i], v);
      }
    }
  }
  __syncthreads();
  if (tid < 384) {
    float inv = 1.0f / rss[tid];
    uss[tid] *= inv;
    vss[tid] *= inv;
  }
  __syncthreads();

  // coefficient production -> GLOBAL C[b][k][q] (coalesced f4 stores)
#pragma unroll
  for (int j = 0; j < 5; ++j) {
    const int k_ = kt + 32 * j;
    const bool pos = (j == 4);
    const float ic0 = css[k_], ic1 = css[160 + k_], ic2 = css[320 + k_];
    float c0a[8];
#pragma unroll
    for (int i = 0; i < 8; ++i) {
      const int q2 = qb + i;
      float a0 = pos ? vss[q2]       : uss[q2];
      float a1 = pos ? vss[128 + q2] : uss[128 + q2];
      float a2 = pos ? vss[256 + q2] : uss[256 + q2];
      float z = zz[i][j], z2 = z * z, z4 = z2 * z2, z10 = z4 * z4 * z2;
      float c = fmaf(z, ic2 * a2, fmaf(z2, ic1 * a1, z10 * (ic0 * a0)));
      c0a[i] = pos ? c : -c;
    }
    const size_t base = ((size_t)b * K + k_) * 32;
    C4g[base + 2 * qg]     = make_float4(c0a[0], c0a[1], c0a[2], c0a[3]);
    C4g[base + 2 * qg + 1] = make_float4(c0a[4], c0a[5], c0a[6], c0a[7]);
  }
}

// ================= K3: drift GEMM (C from global, Y from LDS) + loss =======
// 512 threads, one block/batch, ~41 KB LDS. dr[4][8]=32 acc regs, live ~70.
__global__
__attribute__((amdgpu_flat_work_group_size(512, 512)))
__attribute__((amdgpu_waves_per_eu(2, 4)))
void k_gemm(
    const float* __restrict__ y_pos, const float* __restrict__ y_neg,
    const float4* __restrict__ C4g, double* __restrict__ ws) {
  __shared__ __align__(16) float SM[10240];
  __shared__ double redd[4];
  float4* Y4 = (float4*)SM;

  const int b = blockIdx.x, tid = threadIdx.x;
  const float4* yn4 = (const float4*)(y_neg + (size_t)b * N * D);
  const float4* yp4 = (const float4*)(y_pos + (size_t)b * P * D);
  for (int idx = tid; idx < K * 16; idx += 512) {
    int k = idx >> 4, d4 = idx & 15;
    float4 v = (k < N) ? yn4[k * 16 + d4] : yp4[(k - N) * 16 + d4];
    Y4[k * 16 + ((d4 + k) & 15)] = v;
  }
  __syncthreads();

  const int qc = (tid >> 3) & 31, dc = tid & 7, kc = tid >> 8;
  float dr[4][8];
#pragma unroll
  for (int i = 0; i < 4; ++i)
#pragma unroll
    for (int n = 0; n < 8; ++n) dr[i][n] = 0.f;

  const size_t cbase = (size_t)b * K * 32 + qc;
#pragma unroll 4
  for (int kk = 0; kk < 80; ++kk) {
    const int k_ = kc * 80 + kk;
    float4 cg = C4g[cbase + (size_t)k_ * 32];
    float4 y0 = Y4[k_ * 16 + ((2 * dc + k_) & 15)];
    float4 y1 = Y4[k_ * 16 + ((2 * dc + 1 + k_) & 15)];
#define GACC(ii, cv)                               \
    dr[ii][0] = fmaf(cv, y0.x, dr[ii][0]);         \
    dr[ii][1] = fmaf(cv, y0.y, dr[ii][1]);         \
    dr[ii][2] = fmaf(cv, y0.z, dr[ii][2]);         \
    dr[ii][3] = fmaf(cv, y0.w, dr[ii][3]);         \
    dr[ii][4] = fmaf(cv, y1.x, dr[ii][4]);         \
    dr[ii][5] = fmaf(cv, y1.y, dr[ii][5]);         \
    dr[ii][6] = fmaf(cv, y1.z, dr[ii][6]);         \
    dr[ii][7] = fmaf(cv, y1.w, dr[ii][7]);
    GACC(0, cg.x) GACC(1, cg.y) GACC(2, cg.z) GACC(3, cg.w)
#undef GACC
  }
  __syncthreads();

  // merge kc halves (reuse Y region) + loss
  float4* FB = Y4;
  if (kc == 1) {
#pragma unroll
    for (int i = 0; i < 4; ++i) {
      const int q = qc * 4 + i;
#pragma unroll
      for (int w = 0; w < 2; ++w)
        FB[q * 16 + ((2 * dc + w + q) & 15)] =
            make_float4(dr[i][w*4], dr[i][w*4+1], dr[i][w*4+2], dr[i][w*4+3]);
    }
  }
  __syncthreads();
  if (kc == 0) {
    float tot = 0.f;
#pragma unroll
    for (int i = 0; i < 4; ++i) {
      const int q = qc * 4 + i;
#pragma unroll
      for (int w = 0; w < 2; ++w) {
        float4 v = FB[q * 16 + ((2 * dc + w + q) & 15)];
        float a0 = dr[i][w*4]   + v.x;
        float a1 = dr[i][w*4+1] + v.y;
        float a2 = dr[i][w*4+2] + v.z;
        float a3 = dr[i][w*4+3] + v.w;
        tot = fmaf(a0, a0, tot); tot = fmaf(a1, a1, tot);
        tot = fmaf(a2, a2, tot); tot = fmaf(a3, a3, tot);
      }
    }
#pragma unroll
    for (int m = 1; m < 64; m <<= 1) tot += __shfl_xor(tot, m);
    if ((tid & 63) == 0) redd[tid >> 6] = (double)tot;
  }
  __syncthreads();
  if (tid == 0)
    atomicAdd(ws + 1, redd[0] + redd[1] + redd[2] + redd[3]);
}

// ================= fallback: R5 fused kernel (verified, 208 us) ============
__global__
__attribute__((amdgpu_flat_work_group_size(512, 512)))
__attribute__((amdgpu_waves_per_eu(2, 2)))
void k_drift_fused(
    const float* __restrict__ x, const float* __restrict__ y_pos,
    const float* __restrict__ y_neg, double* __restrict__ ws) {
  __shared__ __align__(16) float SM[33296];
  float4* Y4 = (float4*)SM;
  float4* X4 = (float4*)(SM + 10240);
  float*  Cs = SM + 10240;
  float4* C4 = (float4*)(SM + 10240);
  float* rss = SM + 31360;
  float* css = SM + 31744;
  float* uss = SM + 32224;
  float* vss = SM + 32608;
  float* ysq = SM + 32992;
  float* xsq = SM + 33152;
  double* redd = (double*)(SM + 33280);

  const int b = blockIdx.x, tid = threadIdx.x;
  const float4* yn4 = (const float4*)(y_neg + (size_t)b * N * D);
  const float4* yp4 = (const float4*)(y_pos + (size_t)b * P * D);
  const float4* xg  = (const float4*)(x + (size_t)b * Q * D);

  for (int idx = tid; idx < K * 16; idx += 512) {
    int k = idx >> 4, d4 = idx & 15;
    float4 v = (k < N) ? yn4[k * 16 + d4] : yp4[(k - N) * 16 + d4];
    Y4[k * 16 + ((d4 + k) & 15)] = v;
  }
  for (int idx = tid; idx < Q * 16; idx += 512) {
    int q = idx >> 4, d4 = idx & 15;
    X4[q * 16 + ((d4 + (q >> 3)) & 15)] = xg[q * 16 + d4];
  }
  if (tid < 384) { rss[tid] = 0.f; uss[tid] = 0.f; vss[tid] = 0.f; }
  __syncthreads();
  if (tid < K) {
    float s = 0.f;
#pragma unroll
    for (int c = 0; c < 16; ++c) {
      float4 v = Y4[tid * 16 + ((c + tid) & 15)];
      s = fmaf(v.x, v.x, fmaf(v.y, v.y, fmaf(v.z, v.z, fmaf(v.w, v.w, s))));
    }
    ysq[tid] = s;
  }
  if (tid < Q) {
    float s = 0.f;
#pragma unroll
    for (int c = 0; c < 16; ++c) {
      float4 v = X4[tid * 16 + ((c + tid) & 15)];
      s = fmaf(v.x, v.x, fmaf(v.y, v.y, fmaf(v.z, v.z, fmaf(v.w, v.w, s))));
    }
    xsq[tid] = s;
  }
  __syncthreads();

  const int qg = tid & 15, kt = tid >> 4;
  const int qb = qg * 8, kb0 = kt * 5;

  float zz[8][5];
#pragma unroll
  for (int i = 0; i < 8; ++i)
#pragma unroll
    for (int j = 0; j < 5; ++j) zz[i][j] = 0.f;

#pragma unroll 2
  for (int d4 = 0; d4 < 16; ++d4) {
    float4 yv[5];
#pragma unroll
    for (int j = 0; j < 5; ++j) {
      int k = kb0 + j;
      yv[j] = Y4[k * 16 + ((d4 + k) & 15)];
    }
    const int rx = (d4 + qg) & 15;
#pragma unroll
    for (int i = 0; i < 8; ++i) {
      float4 xv = X4[(qb + i) * 16 + rx];
#pragma unroll
      for (int j = 0; j < 5; ++j)
        zz[i][j] = fmaf(xv.x, yv[j].x, fmaf(xv.y, yv[j].y,
                   fmaf(xv.z, yv[j].z, fmaf(xv.w, yv[j].w, zz[i][j]))));
    }
  }

  const float meand = (float)(ws[0] * (1.0 / ((double)B * Q * P)));
  const float invt2 = 1.0f / fmaxf(meand, 1e-6f);
#pragma unroll
  for (int i = 0; i < 8; ++i)
#pragma unroll
    for (int j = 0; j < 5; ++j) {
      float d2 = xsq[qb + i] + ysq[kb0 + j] - 2.f * zz[i][j];
      zz[i][j] = __expf(-sqrtf(fmaxf(d2, 0.f)) * invt2);
    }

#pragma unroll
  for (int t = 0; t < 3; ++t) {
    float ers[8] = {0.f,0.f,0.f,0.f,0.f,0.f,0.f,0.f};
    float ecs[5] = {0.f,0.f,0.f,0.f,0.f};
#pragma unroll
    for (int i = 0; i < 8; ++i)
#pragma unroll
      for (int j = 0; j < 5; ++j) {
        float z = zz[i][j], f;
        if (t == 2) f = z;
        else if (t == 1) f = z * z;
        else { float z2 = z * z, z4 = z2 * z2; f = z4 * z4 * z2; }
        ers[i] += f; ecs[j] += f;
      }
#pragma unroll
    for (int j = 0; j < 5; ++j) {
      float v = ecs[j];
      v += __shfl_xor(v, 1); v += __shfl_xor(v, 2);
      v += __shfl_xor(v, 4); v += __shfl_xor(v, 8);
      if (qg == 0) css[t * 160 + kb0 + j] = v;
    }
#pragma unroll
    for (int i = 0; i < 8; ++i) {
      float v = ers[i];
      v += __shfl_xor(v, 16); v += __shfl_xor(v, 32);
      if ((kt & 3) == 0) atomicAdd(&rss[t * 128 + qb + i], v);
    }
  }
  __syncthreads();
  if (tid < 480) css[tid] = rsqrtf(css[tid]);
  __syncthreads();

#pragma unroll
  for (int t = 0; t < 3; ++t) {
    float icr[5];
#pragma unroll
    for (int j = 0; j < 5; ++j) icr[j] = css[t * 160 + kb0 + j];
    float uu[8] = {0.f,0.f,0.f,0.f,0.f,0.f,0.f,0.f};
    float vv[8] = {0.f,0.f,0.f,0.f,0.f,0.f,0.f,0.f};
#pragma unroll
    for (int i = 0; i < 8; ++i)
#pragma unroll
      for (int j = 0; j < 5; ++j) {
        float z = zz[i][j], f;
        if (t == 2) f = z;
        else if (t == 1) f = z * z;
        else { float z2 = z * z, z4 = z2 * z2; f = z4 * z4 * z2; }
        float a = f * icr[j];
        bool pos = (kb0 + j >= N);
        uu[i] += pos ? a : 0.f;
        vv[i] += pos ? 0.f : a;
      }
#pragma unroll
    for (int i = 0; i < 8; ++i) {
      float u = uu[i];
      u += __shfl_xor(u, 16); u += __shfl_xor(u, 32);
      float v = vv[i];
      v += __shfl_xor(v, 16); v += __shfl_xor(v, 32);
      if ((kt & 3) == 0) {
        atomicAdd(&uss[t * 128 + qb + i], u);
        atomicAdd(&vss[t * 128 + qb + i], v);
      }
    }
  }
  __syncthreads();
  if (tid < 384) {
    float inv = 1.0f / rss[tid];
    uss[tid] *= inv;
    vss[tid] *= inv;
  }
  __syncthreads();

  {
    float ic0[5], ic1[5], ic2[5];
#pragma unroll
    for (int j = 0; j < 5; ++j) {
      ic0[j] = css[0 * 160 + kb0 + j];
      ic1[j] = css[1 * 160 + kb0 + j];
      ic2[j] = css[2 * 160 + kb0 + j];
    }
#pragma unroll
    for (int i = 0; i < 8; ++i) {
      const int q2 = qb + i;
      float u0 = uss[q2], u1 = uss[128 + q2], u2 = uss[256 + q2];
      float v0 = vss[q2], v1 = vss[128 + q2], v2 = vss[256 + q2];
#pragma unroll
      for (int j = 0; j < 5; ++j) {
        const int k = kb0 + j;
        float z = zz[i][j], z2 = z * z, z4 = z2 * z2, z10 = z4 * z4 * z2;
        bool pos = (k >= N);
        float a0 = pos ? v0 : u0, a1 = pos ? v1 : u1, a2 = pos ? v2 : u2;
        float c = fmaf(z, ic2[j] * a2, fmaf(z2, ic1[j] * a1, z10 * (ic0[j] * a0)));
        Cs[k * 132 + q2] = pos ? c : -c;
      }
    }
  }
  __syncthreads();

  const int kc = tid >> 8, qc = (tid >> 3) & 31, dc = tid & 7;
  float dr[4][8];
#pragma unroll
  for (int i = 0; i < 4; ++i)
#pragma unroll
    for (int n = 0; n < 8; ++n) dr[i][n] = 0.f;

#pragma unroll 4
  for (int kk = 0; kk < 80; ++kk) {
    const int k = kc * 80 + kk;
    float4 ca = C4[k * 33 + qc];
    float4 y0 = Y4[k * 16 + ((dc * 2 + k) & 15)];
    float4 y1 = Y4[k * 16 + ((dc * 2 + 1 + k) & 15)];
#define GACC(ii, cv)                               \
    dr[ii][0] = fmaf(cv, y0.x, dr[ii][0]);         \
    dr[ii][1] = fmaf(cv, y0.y, dr[ii][1]);         \
    dr[ii][2] = fmaf(cv, y0.z, dr[ii][2]);         \
    dr[ii][3] = fmaf(cv, y0.w, dr[ii][3]);         \
    dr[ii][4] = fmaf(cv, y1.x, dr[ii][4]);         \
    dr[ii][5] = fmaf(cv, y1.y, dr[ii][5]);         \
    dr[ii][6] = fmaf(cv, y1.z, dr[ii][6]);         \
    dr[ii][7] = fmaf(cv, y1.w, dr[ii][7]);
    GACC(0, ca.x) GACC(1, ca.y) GACC(2, ca.z) GACC(3, ca.w)
#undef GACC
  }
  __syncthreads();

  float4* FB = Y4;
  if (kc == 1) {
#pragma unroll
    for (int i = 0; i < 4; ++i) {
      const int q = qc * 4 + i;
#pragma unroll
      for (int w = 0; w < 2; ++w)
        FB[q * 16 + ((dc * 2 + w + qc) & 15)] =
            make_float4(dr[i][w*4], dr[i][w*4+1], dr[i][w*4+2], dr[i][w*4+3]);
    }
  }
  __syncthreads();
  if (kc == 0) {
    float tot = 0.f;
#pragma unroll
    for (int i = 0; i < 4; ++i) {
      const int q = qc * 4 + i;
#pragma unroll
      for (int w = 0; w < 2; ++w) {
        float4 v = FB[q * 16 + ((dc * 2 + w + qc) & 15)];
        float a0 = dr[i][w*4]   + v.x;
        float a1 = dr[i][w*4+1] + v.y;
        float a2 = dr[i][w*4+2] + v.z;
        float a3 = dr[i][w*4+3] + v.w;
        tot = fmaf(a0, a0, tot); tot = fmaf(a1, a1, tot);
        tot = fmaf(a2, a2, tot); tot = fmaf(a3, a3, tot);
      }
    }
#pragma unroll
    for (int m = 1; m < 64; m <<= 1) tot += __shfl_xor(tot, m);
    if ((tid & 63) == 0) redd[tid >> 6] = (double)tot;
  }
  __syncthreads();
  if (tid == 0)
    atomicAdd(ws + 1, redd[0] + redd[1] + redd[2] + redd[3]);
}

__global__ void k_final(const double* __restrict__ ws, float* __restrict__ out) {
  out[0] = (float)(ws[1] / ((double)B * Q * D));
}

}  // namespace

extern "C" void kernel_launch(void* const* d_in, const int* in_sizes, int n_in,
                              void* d_out, int out_size, void* d_ws, size_t ws_size,
                              hipStream_t stream) {
  const float* x = (const float*)d_in[0];
  const float* y_pos = (const float*)d_in[1];
  const float* y_neg = (const float*)d_in[2];
  float* out = (float*)d_out;
  double* ws = (double*)d_ws;

  const size_t c_bytes = (size_t)B * K * Q * sizeof(float);   // 80 MB
  hipMemsetAsync(d_ws, 0, 2 * sizeof(double), stream);
  k_meandist<<<B, 256, 0, stream>>>(x, y_pos, ws);
  if (ws_size >= 64 + c_bytes) {
    float4* C4g = (float4*)((char*)d_ws + 64);
    k_coeff<<<B, 512, 0, stream>>>(x, y_pos, y_neg, ws, C4g);
    k_gemm<<<B, 512, 0, stream>>>(y_pos, y_neg, C4g, ws);
  } else {
    k_drift_fused<<<B, 512, 0, stream>>>(x, y_pos, y_neg, ws);
  }
  k_final<<<1, 1, 0, stream>>>(ws, out);
}